// Round 6
// baseline (3980.664 us; speedup 1.0000x reference)
//
#include <hip/hip_runtime.h>
#include <hip/hip_bf16.h>

// B=128, D=768, L=64, QLEN=448. All fp32.
#define B_ 128

// ---------------- positional encoding ----------------
__global__ __launch_bounds__(256) void pe_kernel(float* __restrict__ pe) {
  int idx = blockIdx.x * 256 + threadIdx.x;
  if (idx >= 768 * 64) return;
  int d = idx >> 6, l = idx & 63;
  float df = (float)d;
  float freq, ph;
  if ((d & 1) == 0) { freq = powf(10000.f, -df / 768.f); ph = 0.f; }
  else             { freq = -powf(10000.f, (1.f - df) / 768.f); ph = 1.57079632679489662f; }
  pe[idx] = sinf((float)l * freq + ph);
}

// ---------------- row dots: cw1[b,i]=C.w1, qw2[b,j]=Q.w2 ----------------
__global__ __launch_bounds__(256) void rowdot_kernel(const float* __restrict__ x, const float* __restrict__ W,
                                                     float* __restrict__ cw1, float* __restrict__ qw2) {
  int wid = threadIdx.x >> 6, lane = threadIdx.x & 63;
  int row = blockIdx.x * 4 + wid;           // 0 .. B*512-1
  int b = row >> 9, t = row & 511;
  const float* p = x + (long long)row * 768;
  const float* w = (t < 64) ? W : (W + 768);
  float s = 0.f;
  #pragma unroll
  for (int i = 0; i < 12; i++) s += p[lane + i * 64] * w[lane + i * 64];
  #pragma unroll
  for (int o = 32; o > 0; o >>= 1) s += __shfl_xor(s, o);
  if (lane == 0) { if (t < 64) cw1[b * 64 + t] = s; else qw2[b * 448 + (t - 64)] = s; }
}

// ---------------- generic batched 64x64-tile GEMM ----------------
// Out[b,m,n] = epilogue( alpha * sum_k A(b,m,k)*B(b,k,n) )
// A_KC: A[m*lda+k] (k-contig) else A[k*lda+m] (m-contig)
// B_KC: B[n*ldb+k] (k-contig) else B[k*ldb+n] (n-contig)
// MODE 0: raw*alpha   1: +rowv[b,m]+colv[b,n]   2: relu(+rowv[m])+R   3: +R   5: +rowv[m]
template<int MODE, bool A_KC, bool B_KC, bool AKSC>
__global__ __launch_bounds__(256) void gemm_k(
    const float* __restrict__ Ag, long long Abst, int lda,
    const float* __restrict__ Bg, long long Bbst, int ldb,
    float* __restrict__ Cg, long long Cbst, int ldc,
    const float* __restrict__ Rg,
    const float* __restrict__ rowv, int rowv_b,
    const float* __restrict__ colv, int colv_b,
    const float* __restrict__ ksc,
    int K, float alpha)
{
  __shared__ float As[16 * 68];
  __shared__ float Bs[16 * 68];
  const int b  = blockIdx.z;
  const int n0 = blockIdx.x * 64;
  const int m0 = blockIdx.y * 64;
  const float* A  = Ag + (long long)b * Abst;
  const float* Bp = Bg + (long long)b * Bbst;
  const int t = threadIdx.x;
  const int tx = t & 15, ty = t >> 4;
  float acc[4][4] = {{0.f}};
  for (int kk = 0; kk < K; kk += 16) {
    if (A_KC) {
      const int m = t >> 2, k4 = (t & 3) << 2;
      float4 v = *(const float4*)(A + (long long)(m0 + m) * lda + (kk + k4));
      if (AKSC) { v.x *= ksc[kk+k4]; v.y *= ksc[kk+k4+1]; v.z *= ksc[kk+k4+2]; v.w *= ksc[kk+k4+3]; }
      As[(k4+0)*68 + m] = v.x; As[(k4+1)*68 + m] = v.y;
      As[(k4+2)*68 + m] = v.z; As[(k4+3)*68 + m] = v.w;
    } else {
      const int kl = t >> 4, m4 = (t & 15) << 2;
      float4 v = *(const float4*)(A + (long long)(kk + kl) * lda + (m0 + m4));
      *(float4*)&As[kl*68 + m4] = v;
    }
    if (B_KC) {
      const int n = t >> 2, k4 = (t & 3) << 2;
      float4 v = *(const float4*)(Bp + (long long)(n0 + n) * ldb + (kk + k4));
      Bs[(k4+0)*68 + n] = v.x; Bs[(k4+1)*68 + n] = v.y;
      Bs[(k4+2)*68 + n] = v.z; Bs[(k4+3)*68 + n] = v.w;
    } else {
      const int kl = t >> 4, n4 = (t & 15) << 2;
      float4 v = *(const float4*)(Bp + (long long)(kk + kl) * ldb + (n0 + n4));
      *(float4*)&Bs[kl*68 + n4] = v;
    }
    __syncthreads();
    #pragma unroll
    for (int k = 0; k < 16; k++) {
      float4 a  = *(const float4*)&As[k*68 + (ty << 2)];
      float4 bv = *(const float4*)&Bs[k*68 + (tx << 2)];
      acc[0][0] += a.x*bv.x; acc[0][1] += a.x*bv.y; acc[0][2] += a.x*bv.z; acc[0][3] += a.x*bv.w;
      acc[1][0] += a.y*bv.x; acc[1][1] += a.y*bv.y; acc[1][2] += a.y*bv.z; acc[1][3] += a.y*bv.w;
      acc[2][0] += a.z*bv.x; acc[2][1] += a.z*bv.y; acc[2][2] += a.z*bv.z; acc[2][3] += a.z*bv.w;
      acc[3][0] += a.w*bv.x; acc[3][1] += a.w*bv.y; acc[3][2] += a.w*bv.z; acc[3][3] += a.w*bv.w;
    }
    __syncthreads();
  }
  float* C = Cg + (long long)b * Cbst;
  #pragma unroll
  for (int i = 0; i < 4; i++) {
    const int m = m0 + (ty << 2) + i;
    #pragma unroll
    for (int j = 0; j < 4; j++) {
      const int n = n0 + (tx << 2) + j;
      float v = acc[i][j] * alpha;
      if constexpr (MODE == 1) v += rowv[(long long)b * rowv_b + m] + colv[(long long)b * colv_b + n];
      if constexpr (MODE == 2) { const float* R = Rg + (long long)b * Cbst; v = fmaxf(v + rowv[m], 0.f) + R[(long long)m * ldc + n]; }
      if constexpr (MODE == 3) { const float* R = Rg + (long long)b * Cbst; v += R[(long long)m * ldc + n]; }
      if constexpr (MODE == 5) v += rowv[m];
      C[(long long)m * ldc + n] = v;
    }
  }
}

// ---------------- softmaxes ----------------
__global__ __launch_bounds__(256) void softmax_row448(const float* __restrict__ S, float* __restrict__ S1) {
  int wid = threadIdx.x >> 6, lane = threadIdx.x & 63;
  long long row = (long long)blockIdx.x * 4 + wid;   // B*64 rows
  const float* p = S + row * 448;
  float v[7];
  float m = -1e30f;
  #pragma unroll
  for (int i = 0; i < 7; i++) { v[i] = p[lane + i * 64]; m = fmaxf(m, v[i]); }
  #pragma unroll
  for (int o = 32; o > 0; o >>= 1) m = fmaxf(m, __shfl_xor(m, o));
  float s = 0.f;
  #pragma unroll
  for (int i = 0; i < 7; i++) { v[i] = __expf(v[i] - m); s += v[i]; }
  #pragma unroll
  for (int o = 32; o > 0; o >>= 1) s += __shfl_xor(s, o);
  float inv = 1.f / s;
  float* q = S1 + row * 448;
  #pragma unroll
  for (int i = 0; i < 7; i++) q[lane + i * 64] = v[i] * inv;
}

__global__ __launch_bounds__(256) void softmax_col(const float* __restrict__ S, float* __restrict__ S2) {
  int b = blockIdx.y;
  int j = blockIdx.x * 256 + threadIdx.x;
  if (j >= 448) return;
  const float* p = S + (long long)b * 28672 + j;
  float m = -1e30f;
  for (int i = 0; i < 64; i++) m = fmaxf(m, p[i * 448]);
  float s = 0.f;
  for (int i = 0; i < 64; i++) s += __expf(p[i * 448] - m);
  float inv = 1.f / s;
  float* o = S2 + (long long)b * 28672 + j;
  for (int i = 0; i < 64; i++) o[i * 448] = __expf(p[i * 448] - m) * inv;
}

__global__ __launch_bounds__(256) void softmax_row64(float* __restrict__ A) {
  int wid = threadIdx.x >> 6, lane = threadIdx.x & 63;
  long long row = (long long)blockIdx.x * 4 + wid;   // B*64 rows
  float* p = A + row * 64;
  float v = p[lane];
  float m = v;
  #pragma unroll
  for (int o = 32; o > 0; o >>= 1) m = fmaxf(m, __shfl_xor(m, o));
  v = __expf(v - m);
  float s = v;
  #pragma unroll
  for (int o = 32; o > 0; o >>= 1) s += __shfl_xor(s, o);
  p[lane] = v / s;
}

// ---------------- X0 = transpose(concat([C, A, C*A, C*Bt])) ----------------
__global__ __launch_bounds__(256) void build_x0(const float* __restrict__ x, const float* __restrict__ Ab,
                                                const float* __restrict__ Bt, float* __restrict__ X0) {
  __shared__ float Tsh[64][65];
  int b = blockIdx.y, s = blockIdx.x;        // s: 0..47, 64-channel tile
  int seg = s / 12;
  int cc0 = (s % 12) * 64;
  int tx = threadIdx.x & 63, ty = threadIdx.x >> 6;
  const float* xb  = x  + (long long)b * 393216;
  const float* Abp = Ab + (long long)b * 49152;
  const float* Btp = Bt + (long long)b * 49152;
  for (int ly = ty; ly < 64; ly += 4) {
    int d = cc0 + tx;
    float val;
    if (seg == 0)      val = xb[ly * 768 + d];
    else if (seg == 1) val = Abp[ly * 768 + d];
    else if (seg == 2) val = xb[ly * 768 + d] * Abp[ly * 768 + d];
    else               val = xb[ly * 768 + d] * Btp[ly * 768 + d];
    Tsh[ly][tx] = val;
  }
  __syncthreads();
  long long base = (long long)b * 196608 + (long long)s * 4096;
  for (int ry = ty; ry < 64; ry += 4)
    X0[base + ry * 64 + tx] = Tsh[tx][ry];
}

// ---------------- depthwise conv (k=3 or 5), pad k/2, layout [b][c][64] ----------------
template<int KS, int CH>
__global__ __launch_bounds__(256) void dwconv_kernel(const float* __restrict__ in, const float* __restrict__ w,
                                                     const float* __restrict__ bias, float* __restrict__ out) {
  int idx = blockIdx.x * 256 + threadIdx.x;
  if (idx >= B_ * CH * 64) return;
  int l = idx & 63;
  int c = (idx >> 6) % CH;
  const float* row = in + (idx - l);
  float acc = bias[c];
  #pragma unroll
  for (int tt = 0; tt < KS; tt++) {
    int ll = l + tt - KS / 2;
    if (0 <= ll && ll < 64) acc += row[ll] * w[c * KS + tt];
  }
  out[idx] = acc;
}

// ---------------- layernorm over (D,L) per batch ----------------
__global__ __launch_bounds__(256) void ln_stats(const float* __restrict__ X, float* __restrict__ mu, float* __restrict__ rstd) {
  int b = blockIdx.x;
  const float* p = X + (long long)b * 49152;
  float s = 0.f, s2 = 0.f;
  for (int i = threadIdx.x; i < 49152; i += 256) { float v = p[i]; s += v; s2 += v * v; }
  #pragma unroll
  for (int o = 32; o > 0; o >>= 1) { s += __shfl_down(s, o); s2 += __shfl_down(s2, o); }
  __shared__ float sh[2][4];
  int wid = threadIdx.x >> 6, lane = threadIdx.x & 63;
  if (lane == 0) { sh[0][wid] = s; sh[1][wid] = s2; }
  __syncthreads();
  if (threadIdx.x == 0) {
    s  = sh[0][0] + sh[0][1] + sh[0][2] + sh[0][3];
    s2 = sh[1][0] + sh[1][1] + sh[1][2] + sh[1][3];
    float m = s * (1.f / 49152.f);
    float var = s2 * (1.f / 49152.f) - m * m;
    mu[b] = m; rstd[b] = rsqrtf(var + 1e-5f);
  }
}

__global__ __launch_bounds__(256) void apply_norm(const float* __restrict__ X, const float* __restrict__ mu,
                                                  const float* __restrict__ rstd, const float* __restrict__ w,
                                                  const float* __restrict__ bias, float* __restrict__ out) {
  int idx = blockIdx.x * 256 + threadIdx.x;
  if (idx >= B_ * 49152) return;
  int b = idx / 49152;
  int pd = idx - b * 49152;
  out[idx] = (X[idx] - mu[b]) * rstd[b] * w[pd] + bias[pd];
}

__global__ __launch_bounds__(256) void addpe_kernel(float* __restrict__ X, const float* __restrict__ pe) {
  int idx = blockIdx.x * 256 + threadIdx.x;
  if (idx >= B_ * 49152) return;
  X[idx] += pe[idx % 49152];
}

// ---------------- final head ----------------
__global__ __launch_bounds__(256) void final_head(const float* __restrict__ X, const float* __restrict__ fw,
                                                  const float* __restrict__ fb, float* __restrict__ out) {
  int b = blockIdx.x;
  const float* p = X + (long long)b * 49152;
  float s = 0.f;
  for (int i = threadIdx.x; i < 49152; i += 256) s += p[i] * fw[i];
  #pragma unroll
  for (int o = 32; o > 0; o >>= 1) s += __shfl_down(s, o);
  __shared__ float sh[4];
  int wid = threadIdx.x >> 6, lane = threadIdx.x & 63;
  if (lane == 0) sh[wid] = s;
  __syncthreads();
  if (threadIdx.x == 0) {
    s = sh[0] + sh[1] + sh[2] + sh[3] + fb[0];
    out[b] = 1.f / (1.f + __expf(-s));
  }
}

// ---------------- launcher ----------------
extern "C" void kernel_launch(void* const* d_in, const int* in_sizes, int n_in,
                              void* d_out, int out_size, void* d_ws, size_t ws_size,
                              hipStream_t stream) {
  const float* x       = (const float*)d_in[0];
  const float* W       = (const float*)d_in[1];
  const float* rz_dw_w = (const float*)d_in[2];
  const float* rz_dw_b = (const float*)d_in[3];
  const float* rz_pw_w = (const float*)d_in[4];
  const float* rz_pw_b = (const float*)d_in[5];
  const float* c1_dw_w = (const float*)d_in[6];
  const float* c1_dw_b = (const float*)d_in[7];
  const float* c1_pw_w = (const float*)d_in[8];
  const float* c1_pw_b = (const float*)d_in[9];
  const float* c2_dw_w = (const float*)d_in[10];
  const float* c2_dw_b = (const float*)d_in[11];
  const float* c2_pw_w = (const float*)d_in[12];
  const float* c2_pw_b = (const float*)d_in[13];
  const float* wq      = (const float*)d_in[14];
  const float* wk      = (const float*)d_in[15];
  const float* wv      = (const float*)d_in[16];
  const float* wo      = (const float*)d_in[17];
  const float* fc_w    = (const float*)d_in[18];
  const float* fc_b    = (const float*)d_in[19];
  const float* normb_w = (const float*)d_in[20];
  const float* normb_b = (const float*)d_in[21];
  const float* norm1_w = (const float*)d_in[22];
  const float* norm1_b = (const float*)d_in[23];
  const float* norm2_w = (const float*)d_in[24];
  const float* norm2_b = (const float*)d_in[25];
  const float* norme_w = (const float*)d_in[26];
  const float* norme_b = (const float*)d_in[27];
  const float* fcf_w   = (const float*)d_in[28];
  const float* fcf_b   = (const float*)d_in[29];
  float* out = (float*)d_out;

  float* ws = (float*)d_ws;
  size_t off = 0;
  auto take = [&](size_t n) { float* p = ws + off; off += (n + 63) & ~(size_t)63; return p; };
  float* pe   = take(49152);
  float* cw1  = take((size_t)B_ * 64);
  float* qw2  = take((size_t)B_ * 448);
  float* mu   = take(B_);
  float* rstd = take(B_);
  float* attn = take((size_t)B_ * 64 * 64);
  float* Tb   = take((size_t)B_ * 64 * 64);
  float* BIG  = take((size_t)B_ * 3072 * 64 * 2);   // 50,331,648 floats, heavily reused
  float* Xs1  = take((size_t)B_ * 768 * 64);
  float* Xs2  = take((size_t)B_ * 768 * 64);

  const size_t SL = 6291456;           // one (B,768,64) slab
  // front-end aliasing into BIG (all dead before the slab is re-used):
  float* S   = BIG;                    // slab 0 (dead after softmaxes; X0 written later)
  float* S1  = BIG + 6 * SL;           // slab 6 (dead after A/T gemms)
  float* S2  = BIG + 6 * SL + 3670016; // slabs 6/7
  float* X0  = BIG;                    // slabs 0-3
  float* Abf = BIG + 4 * SL;           // slab 4 (dead after build_x0)
  float* Btb = BIG + 5 * SL;           // slab 5 (dead after build_x0)
  float* Xd  = BIG + 4 * SL;           // slabs 4-7 (overwrites Abf/Btb/S1/S2 after consumed)
  // enc-block aliasing:
  float* Xn  = BIG + 0 * SL; float* tmp = BIG + 1 * SL;
  float* Xa  = BIG + 2 * SL; float* Xb  = BIG + 3 * SL;
  float* q   = BIG + 4 * SL; float* kbf = BIG + 5 * SL;
  float* v   = BIG + 6 * SL; float* av  = BIG + 7 * SL;

  const float* Cx = x;                 // C = x[:, :64, :]
  const float* Qx = x + 49152;         // Q = x[:, 64:, :]

  pe_kernel<<<192, 256, 0, stream>>>(pe);
  rowdot_kernel<<<(B_ * 512) / 4, 256, 0, stream>>>(x, W, cw1, qw2);

  // S[b,i,j] = (C*w3).Q + cw1[b,i] + qw2[b,j]
  gemm_k<1, true, true, true><<<dim3(7, 1, B_), 256, 0, stream>>>(
      Cx, 393216, 768, Qx, 393216, 768, S, 28672, 448, nullptr, cw1, 64, qw2, 448, W + 1536, 768, 1.f);
  softmax_col<<<dim3(2, B_), 256, 0, stream>>>(S, S2);
  softmax_row448<<<(B_ * 64) / 4, 256, 0, stream>>>(S, S1);
  // A = S1 @ Q
  gemm_k<0, true, false, false><<<dim3(12, 1, B_), 256, 0, stream>>>(
      S1, 28672, 448, Qx, 393216, 768, Abf, 49152, 768, nullptr, nullptr, 0, nullptr, 0, nullptr, 448, 1.f);
  // T = S1 @ S2^T
  gemm_k<0, true, true, false><<<dim3(1, 1, B_), 256, 0, stream>>>(
      S1, 28672, 448, S2, 28672, 448, Tb, 4096, 64, nullptr, nullptr, 0, nullptr, 0, nullptr, 448, 1.f);
  // Bt = T @ C
  gemm_k<0, true, false, false><<<dim3(12, 1, B_), 256, 0, stream>>>(
      Tb, 4096, 64, Cx, 393216, 768, Btb, 49152, 768, nullptr, nullptr, 0, nullptr, 0, nullptr, 64, 1.f);

  build_x0<<<dim3(48, B_), 256, 0, stream>>>(x, Abf, Btb, X0);
  dwconv_kernel<5, 3072><<<(B_ * 3072 * 64) / 256, 256, 0, stream>>>(X0, rz_dw_w, rz_dw_b, Xd);
  // X1 = rz_pw @ Xd + b   (768 x 3072 GEMM)
  gemm_k<5, true, false, false><<<dim3(1, 12, B_), 256, 0, stream>>>(
      rz_pw_w, 0, 3072, Xd, 196608, 64, Xs1, 49152, 64, nullptr, rz_pw_b, 0, nullptr, 0, nullptr, 3072, 1.f);

  auto enc = [&](float* Xin, float* Xout) {
    addpe_kernel<<<24576, 256, 0, stream>>>(Xin, pe);
    ln_stats<<<B_, 256, 0, stream>>>(Xin, mu, rstd);
    apply_norm<<<24576, 256, 0, stream>>>(Xin, mu, rstd, normb_w, normb_b, Xn);
    dwconv_kernel<3, 768><<<24576, 256, 0, stream>>>(Xn, c1_dw_w, c1_dw_b, tmp);
    gemm_k<2, true, false, false><<<dim3(1, 12, B_), 256, 0, stream>>>(
        c1_pw_w, 0, 768, tmp, 49152, 64, Xa, 49152, 64, Xin, c1_pw_b, 0, nullptr, 0, nullptr, 768, 1.f);
    ln_stats<<<B_, 256, 0, stream>>>(Xa, mu, rstd);
    apply_norm<<<24576, 256, 0, stream>>>(Xa, mu, rstd, norm1_w, norm1_b, Xn);
    dwconv_kernel<3, 768><<<24576, 256, 0, stream>>>(Xn, c2_dw_w, c2_dw_b, tmp);
    gemm_k<2, true, false, false><<<dim3(1, 12, B_), 256, 0, stream>>>(
        c2_pw_w, 0, 768, tmp, 49152, 64, Xb, 49152, 64, Xa, c2_pw_b, 0, nullptr, 0, nullptr, 768, 1.f);
    ln_stats<<<B_, 256, 0, stream>>>(Xb, mu, rstd);
    apply_norm<<<24576, 256, 0, stream>>>(Xb, mu, rstd, norm2_w, norm2_b, Xn);
    // q/k/v = Xn^T @ w
    gemm_k<0, false, false, false><<<dim3(12, 1, B_), 256, 0, stream>>>(
        Xn, 49152, 64, wq, 0, 768, q, 49152, 768, nullptr, nullptr, 0, nullptr, 0, nullptr, 768, 1.f);
    gemm_k<0, false, false, false><<<dim3(12, 1, B_), 256, 0, stream>>>(
        Xn, 49152, 64, wk, 0, 768, kbf, 49152, 768, nullptr, nullptr, 0, nullptr, 0, nullptr, 768, 1.f);
    gemm_k<0, false, false, false><<<dim3(12, 1, B_), 256, 0, stream>>>(
        Xn, 49152, 64, wv, 0, 768, v, 49152, 768, nullptr, nullptr, 0, nullptr, 0, nullptr, 768, 1.f);
    // attn = softmax(q k^T / sqrt(D))
    gemm_k<0, true, true, false><<<dim3(1, 1, B_), 256, 0, stream>>>(
        q, 49152, 768, kbf, 49152, 768, attn, 4096, 64, nullptr, nullptr, 0, nullptr, 0, nullptr, 768, 0.03608439182435161f);
    softmax_row64<<<(B_ * 64) / 4, 256, 0, stream>>>(attn);
    // av = attn @ v
    gemm_k<0, true, false, false><<<dim3(12, 1, B_), 256, 0, stream>>>(
        attn, 4096, 64, v, 49152, 768, av, 49152, 768, nullptr, nullptr, 0, nullptr, 0, nullptr, 64, 1.f);
    // X4 = (av @ wo)^T + res
    gemm_k<3, false, true, false><<<dim3(1, 12, B_), 256, 0, stream>>>(
        wo, 0, 768, av, 49152, 768, Xa, 49152, 64, Xb, nullptr, 0, nullptr, 0, nullptr, 768, 1.f);
    ln_stats<<<B_, 256, 0, stream>>>(Xa, mu, rstd);
    apply_norm<<<24576, 256, 0, stream>>>(Xa, mu, rstd, norme_w, norme_b, Xn);
    // out = relu(fc_w @ Xn + fc_b) + res
    gemm_k<2, true, false, false><<<dim3(1, 12, B_), 256, 0, stream>>>(
        fc_w, 0, 768, Xn, 49152, 64, Xout, 49152, 64, Xa, fc_b, 0, nullptr, 0, nullptr, 768, 1.f);
  };
  enc(Xs1, Xs2);
  enc(Xs2, Xs1);

  final_head<<<B_, 256, 0, stream>>>(Xs1, fcf_w, fcf_b, out);
}